// Round 1
// baseline (977.321 us; speedup 1.0000x reference)
//
#include <hip/hip_runtime.h>

#define M_ROWS (512*512)
#define NTILES (M_ROWS/64)
#define NBLK_MLP 2048
#define NPART2 NBLK_MLP
#define BN_EPS_F 1e-5f

// ws layout in float units
#define WS_P1   64        // 256 blocks * 24 floats
#define WS_CNT  8192
#define WS_A1   8256      // 4*256 folded W1*a1
#define WS_D1   9280      // 256 folded bias
#define WS_A2   9536      // 256
#define WS_C2   9792      // 256
#define WS_P2   16384     // 2048 * 512 floats (layer2 BN partials)

__device__ __forceinline__ float load_mask(const void* mp, int fmt, int row) {
  return fmt ? (((const unsigned char*)mp)[row] ? 1.f : 0.f)
             : (((const int*)mp)[row] ? 1.f : 0.f);
}

// Detect whether mask buffer is int32 (flag=0) or packed uint8 (flag=1).
// int32 data with values 0/1 has every byte at i%4!=0 equal to 0.
__global__ void detect_mask_kernel(const unsigned char* __restrict__ mb,
                                   int* __restrict__ flag) {
  __shared__ int any;
  if (threadIdx.x == 0) any = 0;
  __syncthreads();
  int c = 0;
  for (int i = threadIdx.x; i < 4096; i += blockDim.x)
    if ((i & 3) && mb[i]) c = 1;
  if (c) atomicOr(&any, 1);
  __syncthreads();
  if (threadIdx.x == 0) *flag = any;
}

// Masked sufficient statistics of x: cnt, sum(x), sum(x x^T)
__global__ __launch_bounds__(256) void stats1_kernel(
    const float* __restrict__ bbox, const void* __restrict__ maskp,
    const int* __restrict__ flagp, float* __restrict__ part) {
  const int t = threadIdx.x;
  const int fmt = *flagp;
  float cnt = 0.f, sx[4] = {0.f,0.f,0.f,0.f}, sxx[16];
  #pragma unroll
  for (int i = 0; i < 16; ++i) sxx[i] = 0.f;
  for (int row = blockIdx.x * 256 + t; row < M_ROWS; row += gridDim.x * 256) {
    float m = load_mask(maskp, fmt, row);
    if (m != 0.f) {
      float4 x = *(const float4*)(bbox + (size_t)row * 16);
      float xv[4] = {x.x, x.y, x.z, x.w};
      cnt += 1.f;
      #pragma unroll
      for (int i = 0; i < 4; ++i) {
        sx[i] += xv[i];
        #pragma unroll
        for (int j = 0; j < 4; ++j) sxx[i*4+j] = fmaf(xv[i], xv[j], sxx[i*4+j]);
      }
    }
  }
  __shared__ float rb[256][22];
  rb[t][0] = cnt;
  #pragma unroll
  for (int i = 0; i < 4; ++i) rb[t][1+i] = sx[i];
  #pragma unroll
  for (int i = 0; i < 16; ++i) rb[t][5+i] = sxx[i];
  __syncthreads();
  for (int off = 128; off > 0; off >>= 1) {
    if (t < off) {
      #pragma unroll
      for (int s = 0; s < 21; ++s) rb[t][s] += rb[t+off][s];
    }
    __syncthreads();
  }
  if (t < 21) part[blockIdx.x * 24 + t] = rb[0][t];
}

// Reduce stats1 partials; compute folded layer-1 weights A1 = W1*a1, d1.
__global__ __launch_bounds__(256) void finalize1_kernel(
    const float* __restrict__ part, const float* __restrict__ W1,
    const float* __restrict__ b1, const float* __restrict__ g1,
    const float* __restrict__ be1, float* __restrict__ wsf) {
  const int t = threadIdx.x;
  __shared__ float s[21];
  if (t < 21) {
    float a = 0.f;
    for (int b = 0; b < 256; ++b) a += part[b*24 + t];
    s[t] = a;
  }
  __syncthreads();
  const float cnt = fmaxf(s[0], 1.f);
  float w[4] = {W1[t], W1[256+t], W1[512+t], W1[768+t]};
  const float b1f = b1[t];
  float sw = 0.f;
  #pragma unroll
  for (int k = 0; k < 4; ++k) sw = fmaf(s[1+k], w[k], sw);
  float qf = 0.f;
  #pragma unroll
  for (int i = 0; i < 4; ++i)
    #pragma unroll
    for (int j = 0; j < 4; ++j) qf = fmaf(s[5+i*4+j]*w[i], w[j], qf);
  const float mu  = sw/cnt + b1f;
  const float eh2 = (qf + 2.f*b1f*sw)/cnt + b1f*b1f;
  const float var = fmaxf(eh2 - mu*mu, 0.f);
  const float a1  = g1[t] * rsqrtf(var + BN_EPS_F);
  const float c1  = be1[t] - mu*a1;
  #pragma unroll
  for (int k = 0; k < 4; ++k) wsf[WS_A1 + k*256 + t] = w[k]*a1;
  wsf[WS_D1 + t] = fmaf(b1f, a1, c1);
  if (t == 0) wsf[WS_CNT] = cnt;
}

// 64-row x 256-col tile GEMM: A (LDS) x W (global) + bias.
// Thread t: fgrp = t&63 -> 4 output features, rgrp = t>>6 -> 16 rows.
__device__ __forceinline__ void gemm_tile(const float* hb, const float* __restrict__ wb,
                                          const float4 bb, float acc[4][16]) {
  #pragma unroll
  for (int i = 0; i < 16; ++i) { acc[0][i]=bb.x; acc[1][i]=bb.y; acc[2][i]=bb.z; acc[3][i]=bb.w; }
  for (int k0 = 0; k0 < 256; k0 += 4) {
    float4 wa = *(const float4*)(wb + (k0+0)*256);
    float4 wbv= *(const float4*)(wb + (k0+1)*256);
    float4 wc = *(const float4*)(wb + (k0+2)*256);
    float4 wd = *(const float4*)(wb + (k0+3)*256);
    #pragma unroll
    for (int i = 0; i < 16; ++i) {
      float4 h = *(const float4*)(hb + i*256 + k0);
      acc[0][i] = fmaf(h.w,wd.x, fmaf(h.z,wc.x, fmaf(h.y,wbv.x, fmaf(h.x,wa.x, acc[0][i]))));
      acc[1][i] = fmaf(h.w,wd.y, fmaf(h.z,wc.y, fmaf(h.y,wbv.y, fmaf(h.x,wa.y, acc[1][i]))));
      acc[2][i] = fmaf(h.w,wd.z, fmaf(h.z,wc.z, fmaf(h.y,wbv.z, fmaf(h.x,wa.z, acc[2][i]))));
      acc[3][i] = fmaf(h.w,wd.w, fmaf(h.z,wc.w, fmaf(h.y,wbv.w, fmaf(h.x,wa.w, acc[3][i]))));
    }
  }
}

// Layer1 (folded BN+ReLU) + Layer2 GEMM; writes h2_pre to hout (=d_out),
// accumulates masked per-feature sum/sumsq partials for layer-2 BN.
__global__ __launch_bounds__(256) void mlp12_kernel(
    const float* __restrict__ bbox, const void* __restrict__ maskp,
    const int* __restrict__ flagp, const float* __restrict__ wsf,
    const float* __restrict__ W2, const float* __restrict__ b2,
    float* __restrict__ hout, float* __restrict__ part2) {
  __shared__ float xs[64][4];
  __shared__ float ms[64];
  __shared__ float h1s[64][256];
  __shared__ float red[4][256];
  const int t = threadIdx.x;
  const int fgrp = t & 63, rgrp = t >> 6;
  const int fmt = *flagp;
  const float a10 = wsf[WS_A1 + t],       a11 = wsf[WS_A1 + 256 + t];
  const float a12 = wsf[WS_A1 + 512 + t], a13 = wsf[WS_A1 + 768 + t];
  const float d1f = wsf[WS_D1 + t];
  const float* w2b = W2 + (fgrp << 2);
  const float4 bb = *(const float4*)(b2 + (fgrp << 2));
  float ps[4] = {0.f,0.f,0.f,0.f}, pq[4] = {0.f,0.f,0.f,0.f};

  for (int tile = blockIdx.x; tile < NTILES; tile += gridDim.x) {
    const int row0 = tile << 6;
    if (t < 64) {
      float4 x4 = *(const float4*)(bbox + (size_t)(row0 + t) * 16);
      xs[t][0] = x4.x; xs[t][1] = x4.y; xs[t][2] = x4.z; xs[t][3] = x4.w;
      ms[t] = load_mask(maskp, fmt, row0 + t);
    }
    __syncthreads();
    for (int r = 0; r < 64; ++r) {
      float v = d1f;
      v = fmaf(xs[r][0], a10, v);
      v = fmaf(xs[r][1], a11, v);
      v = fmaf(xs[r][2], a12, v);
      v = fmaf(xs[r][3], a13, v);
      h1s[r][t] = fmaxf(v, 0.f);
    }
    __syncthreads();
    float acc[4][16];
    gemm_tile(&h1s[rgrp << 4][0], w2b, bb, acc);
    #pragma unroll
    for (int i = 0; i < 16; ++i) {
      const int r = (rgrp << 4) + i;
      const float m = ms[r];
      float4 o; o.x = acc[0][i]; o.y = acc[1][i]; o.z = acc[2][i]; o.w = acc[3][i];
      *(float4*)(hout + (size_t)(row0 + r) * 256 + (fgrp << 2)) = o;
      ps[0] = fmaf(m, o.x, ps[0]); pq[0] = fmaf(m*o.x, o.x, pq[0]);
      ps[1] = fmaf(m, o.y, ps[1]); pq[1] = fmaf(m*o.y, o.y, pq[1]);
      ps[2] = fmaf(m, o.z, ps[2]); pq[2] = fmaf(m*o.z, o.z, pq[2]);
      ps[3] = fmaf(m, o.w, ps[3]); pq[3] = fmaf(m*o.w, o.w, pq[3]);
    }
    __syncthreads();
  }
  #pragma unroll
  for (int j = 0; j < 4; ++j) red[rgrp][(fgrp<<2)+j] = ps[j];
  __syncthreads();
  part2[(size_t)blockIdx.x*512 + t] = red[0][t] + red[1][t] + red[2][t] + red[3][t];
  __syncthreads();
  #pragma unroll
  for (int j = 0; j < 4; ++j) red[rgrp][(fgrp<<2)+j] = pq[j];
  __syncthreads();
  part2[(size_t)blockIdx.x*512 + 256 + t] = red[0][t] + red[1][t] + red[2][t] + red[3][t];
}

// Reduce layer-2 BN partials (one block per feature), write a2/c2.
__global__ __launch_bounds__(256) void finalize2_kernel(
    float* __restrict__ wsf, const float* __restrict__ g2,
    const float* __restrict__ be2) {
  const int f = blockIdx.x, t = threadIdx.x;
  const float* part2 = wsf + WS_P2;
  float s1 = 0.f, s2 = 0.f;
  for (int b = t; b < NPART2; b += 256) {
    s1 += part2[(size_t)b*512 + f];
    s2 += part2[(size_t)b*512 + 256 + f];
  }
  __shared__ float r1[256], r2[256];
  r1[t] = s1; r2[t] = s2;
  __syncthreads();
  for (int off = 128; off > 0; off >>= 1) {
    if (t < off) { r1[t] += r1[t+off]; r2[t] += r2[t+off]; }
    __syncthreads();
  }
  if (t == 0) {
    const float cnt = wsf[WS_CNT];
    const float mu  = r1[0]/cnt;
    const float var = fmaxf(r2[0]/cnt - mu*mu, 0.f);
    const float a2  = g2[f] * rsqrtf(var + BN_EPS_F);
    wsf[WS_A2 + f] = a2;
    wsf[WS_C2 + f] = be2[f] - mu*a2;
  }
}

// Layer-2 BN+ReLU (on the fly) + Layer3 GEMM + mask; reads h2_pre from hout,
// overwrites hout with the final output (same rows per block -> no hazard).
__global__ __launch_bounds__(256) void mlp3_kernel(
    const void* __restrict__ maskp, const int* __restrict__ flagp,
    const float* __restrict__ wsf, const float* __restrict__ W3,
    const float* __restrict__ b3, float* __restrict__ hout) {
  __shared__ float ms[64];
  __shared__ float h1s[64][256];
  const int t = threadIdx.x;
  const int fgrp = t & 63, rgrp = t >> 6;
  const int fmt = *flagp;
  const float a2t = wsf[WS_A2 + t], c2t = wsf[WS_C2 + t];
  const float* w3b = W3 + (fgrp << 2);
  const float4 bb = *(const float4*)(b3 + (fgrp << 2));

  for (int tile = blockIdx.x; tile < NTILES; tile += gridDim.x) {
    const int row0 = tile << 6;
    if (t < 64) ms[t] = load_mask(maskp, fmt, row0 + t);
    for (int r = 0; r < 64; ++r) {
      float v = hout[(size_t)(row0 + r)*256 + t];
      h1s[r][t] = fmaxf(fmaf(v, a2t, c2t), 0.f);
    }
    __syncthreads();
    float acc[4][16];
    gemm_tile(&h1s[rgrp << 4][0], w3b, bb, acc);
    #pragma unroll
    for (int i = 0; i < 16; ++i) {
      const int r = (rgrp << 4) + i;
      const float m = ms[r];
      float4 o; o.x = acc[0][i]*m; o.y = acc[1][i]*m; o.z = acc[2][i]*m; o.w = acc[3][i]*m;
      *(float4*)(hout + (size_t)(row0 + r) * 256 + (fgrp << 2)) = o;
    }
    __syncthreads();
  }
}

extern "C" void kernel_launch(void* const* d_in, const int* in_sizes, int n_in,
                              void* d_out, int out_size, void* d_ws, size_t ws_size,
                              hipStream_t stream) {
  (void)in_sizes; (void)n_in; (void)out_size; (void)ws_size;
  const float* bbox = (const float*)d_in[0];
  const void*  maskp= d_in[1];
  const float* W1 = (const float*)d_in[2];
  const float* b1 = (const float*)d_in[3];
  const float* g1 = (const float*)d_in[4];
  const float* be1= (const float*)d_in[5];
  const float* W2 = (const float*)d_in[6];
  const float* b2 = (const float*)d_in[7];
  const float* g2 = (const float*)d_in[8];
  const float* be2= (const float*)d_in[9];
  const float* W3 = (const float*)d_in[10];
  const float* b3 = (const float*)d_in[11];
  float* out = (float*)d_out;
  float* wsf = (float*)d_ws;
  int*   flag= (int*)d_ws;

  hipLaunchKernelGGL(detect_mask_kernel, dim3(1), dim3(256), 0, stream,
                     (const unsigned char*)maskp, flag);
  hipLaunchKernelGGL(stats1_kernel, dim3(256), dim3(256), 0, stream,
                     bbox, maskp, flag, wsf + WS_P1);
  hipLaunchKernelGGL(finalize1_kernel, dim3(1), dim3(256), 0, stream,
                     wsf + WS_P1, W1, b1, g1, be1, wsf);
  hipLaunchKernelGGL(mlp12_kernel, dim3(NBLK_MLP), dim3(256), 0, stream,
                     bbox, maskp, flag, wsf, W2, b2, out, wsf + WS_P2);
  hipLaunchKernelGGL(finalize2_kernel, dim3(256), dim3(256), 0, stream,
                     wsf, g2, be2);
  hipLaunchKernelGGL(mlp3_kernel, dim3(NBLK_MLP), dim3(256), 0, stream,
                     maskp, flag, wsf, W3, b3, out);
}

// Round 2
// 507.751 us; speedup vs baseline: 1.9248x; 1.9248x over previous
//
#include <hip/hip_runtime.h>

typedef __attribute__((ext_vector_type(8))) short short8;
typedef __attribute__((ext_vector_type(4))) float f32x4;

#define M_ROWS (512*512)
#define NTILES (M_ROWS/64)
#define GRID_MLP 512
#define BN_EPS_F 1e-5f

// ws layout in float units
#define WS_FLAG 0
#define WS_P1   64        // 256 blocks * 24 floats (stats1 partials)
#define WS_CNT  8192
#define WS_A1   8256      // 4*256 folded W1*a1
#define WS_D1   9280      // 256 folded bias
#define WS_A2   9536      // 256
#define WS_C2   9792      // 256
#define WS_W2T  10240     // ushort[65536] = 32768 floats (W2^T bf16 [n][k])
#define WS_W3T  43008     // ushort[65536]
#define WS_P2   76800     // 512 blocks * 512 floats (layer2 BN partials)

__device__ __forceinline__ float load_mask(const void* mp, int fmt, int row) {
  return fmt ? (((const unsigned char*)mp)[row] ? 1.f : 0.f)
             : (((const int*)mp)[row] ? 1.f : 0.f);
}

__device__ __forceinline__ ushort f2bf(float f) {
  unsigned int u = __float_as_uint(f);
  u += 0x7FFFu + ((u >> 16) & 1u);   // RNE
  return (ushort)(u >> 16);
}

// Detect whether mask buffer is int32 (flag=0) or packed uint8 (flag=1).
__global__ void detect_mask_kernel(const unsigned char* __restrict__ mb,
                                   int* __restrict__ flag) {
  __shared__ int any;
  if (threadIdx.x == 0) any = 0;
  __syncthreads();
  int c = 0;
  for (int i = threadIdx.x; i < 4096; i += blockDim.x)
    if ((i & 3) && mb[i]) c = 1;
  if (c) atomicOr(&any, 1);
  __syncthreads();
  if (threadIdx.x == 0) *flag = any;
}

// Masked sufficient statistics of x: cnt, sum(x), sum(x x^T)
__global__ __launch_bounds__(256) void stats1_kernel(
    const float* __restrict__ bbox, const void* __restrict__ maskp,
    const int* __restrict__ flagp, float* __restrict__ part) {
  const int t = threadIdx.x;
  const int fmt = *flagp;
  float cnt = 0.f, sx[4] = {0.f,0.f,0.f,0.f}, sxx[16];
  #pragma unroll
  for (int i = 0; i < 16; ++i) sxx[i] = 0.f;
  for (int row = blockIdx.x * 256 + t; row < M_ROWS; row += gridDim.x * 256) {
    float m = load_mask(maskp, fmt, row);
    if (m != 0.f) {
      float4 x = *(const float4*)(bbox + (size_t)row * 16);
      float xv[4] = {x.x, x.y, x.z, x.w};
      cnt += 1.f;
      #pragma unroll
      for (int i = 0; i < 4; ++i) {
        sx[i] += xv[i];
        #pragma unroll
        for (int j = 0; j < 4; ++j) sxx[i*4+j] = fmaf(xv[i], xv[j], sxx[i*4+j]);
      }
    }
  }
  __shared__ float rb[256][22];
  rb[t][0] = cnt;
  #pragma unroll
  for (int i = 0; i < 4; ++i) rb[t][1+i] = sx[i];
  #pragma unroll
  for (int i = 0; i < 16; ++i) rb[t][5+i] = sxx[i];
  __syncthreads();
  for (int off = 128; off > 0; off >>= 1) {
    if (t < off) {
      #pragma unroll
      for (int s = 0; s < 21; ++s) rb[t][s] += rb[t+off][s];
    }
    __syncthreads();
  }
  if (t < 21) part[blockIdx.x * 24 + t] = rb[0][t];
}

// Reduce stats1 partials; compute folded layer-1 weights A1 = W1*a1, d1.
__global__ __launch_bounds__(256) void finalize1_kernel(
    const float* __restrict__ part, const float* __restrict__ W1,
    const float* __restrict__ b1, const float* __restrict__ g1,
    const float* __restrict__ be1, float* __restrict__ wsf) {
  const int t = threadIdx.x;
  __shared__ float s[21];
  if (t < 21) {
    float a = 0.f;
    for (int b = 0; b < 256; ++b) a += part[b*24 + t];
    s[t] = a;
  }
  __syncthreads();
  const float cnt = fmaxf(s[0], 1.f);
  float w[4] = {W1[t], W1[256+t], W1[512+t], W1[768+t]};
  const float b1f = b1[t];
  float sw = 0.f;
  #pragma unroll
  for (int k = 0; k < 4; ++k) sw = fmaf(s[1+k], w[k], sw);
  float qf = 0.f;
  #pragma unroll
  for (int i = 0; i < 4; ++i)
    #pragma unroll
    for (int j = 0; j < 4; ++j) qf = fmaf(s[5+i*4+j]*w[i], w[j], qf);
  const float mu  = sw/cnt + b1f;
  const float eh2 = (qf + 2.f*b1f*sw)/cnt + b1f*b1f;
  const float var = fmaxf(eh2 - mu*mu, 0.f);
  const float a1  = g1[t] * rsqrtf(var + BN_EPS_F);
  const float c1  = be1[t] - mu*a1;
  #pragma unroll
  for (int k = 0; k < 4; ++k) wsf[WS_A1 + k*256 + t] = w[k]*a1;
  wsf[WS_D1 + t] = fmaf(b1f, a1, c1);
  if (t == 0) wsf[WS_CNT] = cnt;
}

// Convert W2, W3 (fp32 [k][n]) to bf16 transposed [n][k] in ws.
__global__ __launch_bounds__(256) void prep_weights(
    const float* __restrict__ W2, const float* __restrict__ W3,
    float* __restrict__ wsf) {
  const int n = blockIdx.x & 255;
  const int t = threadIdx.x;
  const float* W = (blockIdx.x < 256) ? W2 : W3;
  ushort* dst = (ushort*)(wsf + ((blockIdx.x < 256) ? WS_W2T : WS_W3T));
  dst[n*256 + t] = f2bf(W[t*256 + n]);
}

// h1 = relu(d1 + x @ A1), bf16, swizzled into LDS [64][256].
__device__ __forceinline__ void compute_h1(
    const float (*xs)[4], ushort* h1s, int t,
    const float a1c[4][2], const float d1c[2]) {
  const int c0 = (t & 127) * 2;
  const int r0 = (t >> 7) * 32;
  #pragma unroll 4
  for (int rr = 0; rr < 32; ++rr) {
    const int r = r0 + rr;
    const float x0 = xs[r][0], x1 = xs[r][1], x2 = xs[r][2], x3 = xs[r][3];
    float v0 = d1c[0], v1 = d1c[1];
    v0 = fmaf(x0, a1c[0][0], v0); v1 = fmaf(x0, a1c[0][1], v1);
    v0 = fmaf(x1, a1c[1][0], v0); v1 = fmaf(x1, a1c[1][1], v1);
    v0 = fmaf(x2, a1c[2][0], v0); v1 = fmaf(x2, a1c[2][1], v1);
    v0 = fmaf(x3, a1c[3][0], v0); v1 = fmaf(x3, a1c[3][1], v1);
    v0 = fmaxf(v0, 0.f); v1 = fmaxf(v1, 0.f);
    unsigned int pk = (unsigned int)f2bf(v0) | ((unsigned int)f2bf(v1) << 16);
    unsigned int byte = (unsigned int)r*512u + (unsigned int)c0*2u;
    byte ^= (unsigned int)(r & 7) << 4;
    *(unsigned int*)((char*)h1s + byte) = pk;
  }
}

// Stage a 256-col x 64-k chunk of W^T (bf16 [n][256]) into swizzled LDS.
__device__ __forceinline__ void stage_B(const ushort* __restrict__ Wt,
                                        ushort* Bs, int t, int k0) {
  #pragma unroll
  for (int j = 0; j < 8; ++j) {
    const int v = t + j*256;
    const int col = v >> 3, kr8 = v & 7;
    short8 d = *(const short8*)(Wt + col*256 + k0 + kr8*8);
    unsigned int byte = (unsigned int)col*128u + (unsigned int)kr8*16u;
    byte ^= (unsigned int)(col & 7) << 4;
    *(short8*)((char*)Bs + byte) = d;
  }
}

// One 64-k chunk of MFMA work. acc[rf][cf]: wave covers cols wave*64..+63.
__device__ __forceinline__ void gemm_chunk(const ushort* h1s, const ushort* Bs,
                                           int lane, int wave, int k0,
                                           f32x4 acc[4][4]) {
  #pragma unroll
  for (int ks = 0; ks < 2; ++ks) {
    short8 aF[4];
    #pragma unroll
    for (int rf = 0; rf < 4; ++rf) {
      const int row = rf*16 + (lane & 15);
      unsigned int byte = (unsigned int)row*512u +
                          (unsigned int)((k0 + ks*32 + ((lane >> 4) * 8)) * 2);
      byte ^= (unsigned int)(row & 7) << 4;
      aF[rf] = *(const short8*)((const char*)h1s + byte);
    }
    #pragma unroll
    for (int cf = 0; cf < 4; ++cf) {
      const int col = wave*64 + cf*16 + (lane & 15);
      unsigned int byte = (unsigned int)col*128u +
                          (unsigned int)((ks*32 + ((lane >> 4) * 8)) * 2);
      byte ^= (unsigned int)(col & 7) << 4;
      short8 bF = *(const short8*)((const char*)Bs + byte);
      #pragma unroll
      for (int rf = 0; rf < 4; ++rf)
        acc[rf][cf] = __builtin_amdgcn_mfma_f32_16x16x32_bf16(aF[rf], bF, acc[rf][cf], 0, 0, 0);
    }
  }
}

// Pass A: recompute h1, GEMM2 (MFMA), masked per-feature sum/sumsq partials.
__global__ __launch_bounds__(256, 2) void stats2_mfma(
    const float* __restrict__ bbox, const void* __restrict__ maskp,
    const int* __restrict__ flagp, const float* wsf,
    const float* __restrict__ b2, float* __restrict__ part2) {
  __shared__ float xs[64][4];
  __shared__ float ms[64];
  __shared__ ushort h1s[64*256];
  __shared__ ushort Bs[256*64];
  const int t = threadIdx.x, lane = t & 63, wave = t >> 6;
  const int fmt = *flagp;
  float a1c[4][2], d1c[2];
  {
    const int c0 = (t & 127) * 2;
    #pragma unroll
    for (int j = 0; j < 4; ++j) {
      a1c[j][0] = wsf[WS_A1 + j*256 + c0];
      a1c[j][1] = wsf[WS_A1 + j*256 + c0 + 1];
    }
    d1c[0] = wsf[WS_D1 + c0]; d1c[1] = wsf[WS_D1 + c0 + 1];
  }
  const ushort* W2T = (const ushort*)(wsf + WS_W2T);
  float b2v[4];
  #pragma unroll
  for (int cf = 0; cf < 4; ++cf) b2v[cf] = b2[wave*64 + cf*16 + (lane & 15)];
  float pS[4] = {0,0,0,0}, pQ[4] = {0,0,0,0};

  for (int tile = blockIdx.x; tile < NTILES; tile += GRID_MLP) {
    const int row0 = tile << 6;
    __syncthreads();
    if (t < 64) {
      float4 x4 = *(const float4*)(bbox + (size_t)(row0 + t) * 16);
      xs[t][0] = x4.x; xs[t][1] = x4.y; xs[t][2] = x4.z; xs[t][3] = x4.w;
      ms[t] = load_mask(maskp, fmt, row0 + t);
    }
    __syncthreads();
    compute_h1(xs, h1s, t, a1c, d1c);
    f32x4 acc[4][4];
    #pragma unroll
    for (int rf = 0; rf < 4; ++rf)
      #pragma unroll
      for (int cf = 0; cf < 4; ++cf)
        acc[rf][cf] = (f32x4){b2v[cf], b2v[cf], b2v[cf], b2v[cf]};
    #pragma unroll
    for (int kc = 0; kc < 4; ++kc) {
      __syncthreads();
      stage_B(W2T, Bs, t, kc*64);
      __syncthreads();
      gemm_chunk(h1s, Bs, lane, wave, kc*64, acc);
    }
    float mr[4][4];
    #pragma unroll
    for (int rf = 0; rf < 4; ++rf)
      #pragma unroll
      for (int r = 0; r < 4; ++r)
        mr[rf][r] = ms[rf*16 + ((lane >> 4) * 4) + r];
    #pragma unroll
    for (int cf = 0; cf < 4; ++cf)
      #pragma unroll
      for (int rf = 0; rf < 4; ++rf)
        #pragma unroll
        for (int r = 0; r < 4; ++r) {
          const float m = mr[rf][r];
          const float v = acc[rf][cf][r];
          pS[cf] = fmaf(m, v, pS[cf]);
          pQ[cf] = fmaf(m*v, v, pQ[cf]);
        }
  }
  #pragma unroll
  for (int cf = 0; cf < 4; ++cf) {
    pS[cf] += __shfl_xor(pS[cf], 16); pS[cf] += __shfl_xor(pS[cf], 32);
    pQ[cf] += __shfl_xor(pQ[cf], 16); pQ[cf] += __shfl_xor(pQ[cf], 32);
  }
  if (lane < 16) {
    #pragma unroll
    for (int cf = 0; cf < 4; ++cf) {
      const int col = wave*64 + cf*16 + lane;
      part2[(size_t)blockIdx.x*512 + col] = pS[cf];
      part2[(size_t)blockIdx.x*512 + 256 + col] = pQ[cf];
    }
  }
}

// Reduce layer-2 BN partials (one block per feature), write a2/c2.
__global__ __launch_bounds__(256) void finalize2_kernel(
    float* __restrict__ wsf, const float* __restrict__ g2,
    const float* __restrict__ be2) {
  const int f = blockIdx.x, t = threadIdx.x;
  const float* part2 = wsf + WS_P2;
  float s1 = 0.f, s2 = 0.f;
  for (int b = t; b < GRID_MLP; b += 256) {
    s1 += part2[(size_t)b*512 + f];
    s2 += part2[(size_t)b*512 + 256 + f];
  }
  __shared__ float r1[256], r2[256];
  r1[t] = s1; r2[t] = s2;
  __syncthreads();
  for (int off = 128; off > 0; off >>= 1) {
    if (t < off) { r1[t] += r1[t+off]; r2[t] += r2[t+off]; }
    __syncthreads();
  }
  if (t == 0) {
    const float cnt = wsf[WS_CNT];
    const float mu  = r1[0]/cnt;
    const float var = fmaxf(r2[0]/cnt - mu*mu, 0.f);
    const float a2  = g2[f] * rsqrtf(var + BN_EPS_F);
    wsf[WS_A2 + f] = a2;
    wsf[WS_C2 + f] = be2[f] - mu*a2;
  }
}

// Pass B: h1 -> GEMM2 -> BN2+ReLU -> GEMM3 -> mask -> out. All MFMA.
__global__ __launch_bounds__(256, 2) void mlp3_mfma(
    const float* __restrict__ bbox, const void* __restrict__ maskp,
    const int* __restrict__ flagp, const float* wsf,
    const float* __restrict__ b2, const float* __restrict__ b3,
    float* __restrict__ out) {
  __shared__ float xs[64][4];
  __shared__ float ms[64];
  __shared__ ushort h1s[64*256];
  __shared__ ushort Bs[256*64];
  const int t = threadIdx.x, lane = t & 63, wave = t >> 6;
  const int fmt = *flagp;
  float a1c[4][2], d1c[2];
  {
    const int c0 = (t & 127) * 2;
    #pragma unroll
    for (int j = 0; j < 4; ++j) {
      a1c[j][0] = wsf[WS_A1 + j*256 + c0];
      a1c[j][1] = wsf[WS_A1 + j*256 + c0 + 1];
    }
    d1c[0] = wsf[WS_D1 + c0]; d1c[1] = wsf[WS_D1 + c0 + 1];
  }
  const ushort* W2T = (const ushort*)(wsf + WS_W2T);
  const ushort* W3T = (const ushort*)(wsf + WS_W3T);
  float b2v[4], b3v[4], a2v[4], c2v[4];
  #pragma unroll
  for (int cf = 0; cf < 4; ++cf) {
    const int col = wave*64 + cf*16 + (lane & 15);
    b2v[cf] = b2[col]; b3v[cf] = b3[col];
    a2v[cf] = wsf[WS_A2 + col]; c2v[cf] = wsf[WS_C2 + col];
  }

  for (int tile = blockIdx.x; tile < NTILES; tile += GRID_MLP) {
    const int row0 = tile << 6;
    __syncthreads();
    if (t < 64) {
      float4 x4 = *(const float4*)(bbox + (size_t)(row0 + t) * 16);
      xs[t][0] = x4.x; xs[t][1] = x4.y; xs[t][2] = x4.z; xs[t][3] = x4.w;
      ms[t] = load_mask(maskp, fmt, row0 + t);
    }
    __syncthreads();
    compute_h1(xs, h1s, t, a1c, d1c);
    f32x4 acc[4][4];
    #pragma unroll
    for (int rf = 0; rf < 4; ++rf)
      #pragma unroll
      for (int cf = 0; cf < 4; ++cf)
        acc[rf][cf] = (f32x4){b2v[cf], b2v[cf], b2v[cf], b2v[cf]};
    #pragma unroll
    for (int kc = 0; kc < 4; ++kc) {
      __syncthreads();
      stage_B(W2T, Bs, t, kc*64);
      __syncthreads();
      gemm_chunk(h1s, Bs, lane, wave, kc*64, acc);
    }
    // BN2 + ReLU -> h2 (bf16) overwrites h1s
    __syncthreads();
    #pragma unroll
    for (int rf = 0; rf < 4; ++rf)
      #pragma unroll
      for (int cf = 0; cf < 4; ++cf) {
        const int col = wave*64 + cf*16 + (lane & 15);
        #pragma unroll
        for (int r = 0; r < 4; ++r) {
          const float v = fmaxf(fmaf(acc[rf][cf][r], a2v[cf], c2v[cf]), 0.f);
          const int row = rf*16 + ((lane >> 4) * 4) + r;
          unsigned int byte = (unsigned int)row*512u + (unsigned int)col*2u;
          byte ^= (unsigned int)(row & 7) << 4;
          *(ushort*)((char*)h1s + byte) = f2bf(v);
        }
      }
    #pragma unroll
    for (int rf = 0; rf < 4; ++rf)
      #pragma unroll
      for (int cf = 0; cf < 4; ++cf)
        acc[rf][cf] = (f32x4){b3v[cf], b3v[cf], b3v[cf], b3v[cf]};
    #pragma unroll
    for (int kc = 0; kc < 4; ++kc) {
      __syncthreads();
      stage_B(W3T, Bs, t, kc*64);
      __syncthreads();
      gemm_chunk(h1s, Bs, lane, wave, kc*64, acc);
    }
    #pragma unroll
    for (int rf = 0; rf < 4; ++rf)
      #pragma unroll
      for (int cf = 0; cf < 4; ++cf) {
        const int col = wave*64 + cf*16 + (lane & 15);
        #pragma unroll
        for (int r = 0; r < 4; ++r) {
          const int row = rf*16 + ((lane >> 4) * 4) + r;
          out[(size_t)(row0 + row)*256 + col] = acc[rf][cf][r] * ms[row];
        }
      }
  }
}

extern "C" void kernel_launch(void* const* d_in, const int* in_sizes, int n_in,
                              void* d_out, int out_size, void* d_ws, size_t ws_size,
                              hipStream_t stream) {
  (void)in_sizes; (void)n_in; (void)out_size; (void)ws_size;
  const float* bbox = (const float*)d_in[0];
  const void*  maskp= d_in[1];
  const float* W1 = (const float*)d_in[2];
  const float* b1 = (const float*)d_in[3];
  const float* g1 = (const float*)d_in[4];
  const float* be1= (const float*)d_in[5];
  const float* W2 = (const float*)d_in[6];
  const float* b2 = (const float*)d_in[7];
  const float* g2 = (const float*)d_in[8];
  const float* be2= (const float*)d_in[9];
  const float* W3 = (const float*)d_in[10];
  const float* b3 = (const float*)d_in[11];
  float* out = (float*)d_out;
  float* wsf = (float*)d_ws;
  int*   flag= (int*)d_ws;

  hipLaunchKernelGGL(detect_mask_kernel, dim3(1), dim3(256), 0, stream,
                     (const unsigned char*)maskp, flag);
  hipLaunchKernelGGL(stats1_kernel, dim3(256), dim3(256), 0, stream,
                     bbox, maskp, flag, wsf + WS_P1);
  hipLaunchKernelGGL(finalize1_kernel, dim3(1), dim3(256), 0, stream,
                     wsf + WS_P1, W1, b1, g1, be1, wsf);
  hipLaunchKernelGGL(prep_weights, dim3(512), dim3(256), 0, stream,
                     W2, W3, wsf);
  hipLaunchKernelGGL(stats2_mfma, dim3(GRID_MLP), dim3(256), 0, stream,
                     bbox, maskp, flag, wsf, b2, wsf + WS_P2);
  hipLaunchKernelGGL(finalize2_kernel, dim3(256), dim3(256), 0, stream,
                     wsf, g2, be2);
  hipLaunchKernelGGL(mlp3_mfma, dim3(GRID_MLP), dim3(256), 0, stream,
                     bbox, maskp, flag, wsf, b2, b3, out);
}

// Round 4
// 469.571 us; speedup vs baseline: 2.0813x; 1.0813x over previous
//
#include <hip/hip_runtime.h>

typedef __attribute__((ext_vector_type(8))) short short8;
typedef __attribute__((ext_vector_type(4))) float f32x4;

#define M_ROWS (512*512)
#define NTILES (M_ROWS/64)
#define GRID_STATS 512
#define GRID_MLP 512
#define BN_EPS_F 1e-5f

// ws layout in float units
#define WS_FLAG 0
#define WS_P1   64        // 256 blocks * 24 floats (stats1 partials)
#define WS_CNT  8192
#define WS_A1   8256      // 4*256 folded W1*a1
#define WS_D1   9280      // 256 folded bias
#define WS_A2   9536      // 256
#define WS_C2   9792      // 256
#define WS_W2T  10240     // ushort[65536] = 32768 floats (W2^T bf16 [n][k])
#define WS_W3T  43008     // ushort[65536]
#define WS_P2   76800     // 512 blocks * 512 floats (layer2 BN partials)

__device__ __forceinline__ float load_mask(const void* mp, int fmt, int row) {
  return fmt ? (((const unsigned char*)mp)[row] ? 1.f : 0.f)
             : (((const int*)mp)[row] ? 1.f : 0.f);
}

__device__ __forceinline__ ushort f2bf(float f) {
  unsigned int u = __float_as_uint(f);
  u += 0x7FFFu + ((u >> 16) & 1u);   // RNE
  return (ushort)(u >> 16);
}

// cstage swizzle: XOR byte bits 4-6 with (bits 7-9 ^ bits 10-12). Involution.
__device__ __forceinline__ unsigned cswz(unsigned byte) {
  unsigned key = ((byte >> 7) ^ (byte >> 10)) & 7u;
  return byte ^ (key << 4);
}

// Detect whether mask buffer is int32 (flag=0) or packed uint8 (flag=1).
__global__ void detect_mask_kernel(const unsigned char* __restrict__ mb,
                                   int* __restrict__ flag) {
  __shared__ int any;
  if (threadIdx.x == 0) any = 0;
  __syncthreads();
  int c = 0;
  for (int i = threadIdx.x; i < 4096; i += blockDim.x)
    if ((i & 3) && mb[i]) c = 1;
  if (c) atomicOr(&any, 1);
  __syncthreads();
  if (threadIdx.x == 0) *flag = any;
}

// Masked sufficient statistics of x: cnt, sum(x), sum(x x^T)
__global__ __launch_bounds__(256) void stats1_kernel(
    const float* __restrict__ bbox, const void* __restrict__ maskp,
    const int* __restrict__ flagp, float* __restrict__ part) {
  const int t = threadIdx.x;
  const int fmt = *flagp;
  float cnt = 0.f, sx[4] = {0.f,0.f,0.f,0.f}, sxx[16];
  #pragma unroll
  for (int i = 0; i < 16; ++i) sxx[i] = 0.f;
  for (int row = blockIdx.x * 256 + t; row < M_ROWS; row += gridDim.x * 256) {
    float m = load_mask(maskp, fmt, row);
    if (m != 0.f) {
      float4 x = *(const float4*)(bbox + (size_t)row * 16);
      float xv[4] = {x.x, x.y, x.z, x.w};
      cnt += 1.f;
      #pragma unroll
      for (int i = 0; i < 4; ++i) {
        sx[i] += xv[i];
        #pragma unroll
        for (int j = 0; j < 4; ++j) sxx[i*4+j] = fmaf(xv[i], xv[j], sxx[i*4+j]);
      }
    }
  }
  __shared__ float rb[256][22];
  rb[t][0] = cnt;
  #pragma unroll
  for (int i = 0; i < 4; ++i) rb[t][1+i] = sx[i];
  #pragma unroll
  for (int i = 0; i < 16; ++i) rb[t][5+i] = sxx[i];
  __syncthreads();
  for (int off = 128; off > 0; off >>= 1) {
    if (t < off) {
      #pragma unroll
      for (int s = 0; s < 21; ++s) rb[t][s] += rb[t+off][s];
    }
    __syncthreads();
  }
  if (t < 21) part[blockIdx.x * 24 + t] = rb[0][t];
}

// Reduce stats1 partials; compute folded layer-1 weights A1 = W1*a1, d1.
__global__ __launch_bounds__(256) void finalize1_kernel(
    const float* __restrict__ part, const float* __restrict__ W1,
    const float* __restrict__ b1, const float* __restrict__ g1,
    const float* __restrict__ be1, float* __restrict__ wsf) {
  const int t = threadIdx.x;
  __shared__ float s[21];
  if (t < 21) {
    float a = 0.f;
    for (int b = 0; b < 256; ++b) a += part[b*24 + t];
    s[t] = a;
  }
  __syncthreads();
  const float cnt = fmaxf(s[0], 1.f);
  float w[4] = {W1[t], W1[256+t], W1[512+t], W1[768+t]};
  const float b1f = b1[t];
  float sw = 0.f;
  #pragma unroll
  for (int k = 0; k < 4; ++k) sw = fmaf(s[1+k], w[k], sw);
  float qf = 0.f;
  #pragma unroll
  for (int i = 0; i < 4; ++i)
    #pragma unroll
    for (int j = 0; j < 4; ++j) qf = fmaf(s[5+i*4+j]*w[i], w[j], qf);
  const float mu  = sw/cnt + b1f;
  const float eh2 = (qf + 2.f*b1f*sw)/cnt + b1f*b1f;
  const float var = fmaxf(eh2 - mu*mu, 0.f);
  const float a1  = g1[t] * rsqrtf(var + BN_EPS_F);
  const float c1  = be1[t] - mu*a1;
  #pragma unroll
  for (int k = 0; k < 4; ++k) wsf[WS_A1 + k*256 + t] = w[k]*a1;
  wsf[WS_D1 + t] = fmaf(b1f, a1, c1);
  if (t == 0) wsf[WS_CNT] = cnt;
}

// Convert W2, W3 (fp32 [k][n]) to bf16 transposed [n][k] in ws.
__global__ __launch_bounds__(256) void prep_weights(
    const float* __restrict__ W2, const float* __restrict__ W3,
    float* __restrict__ wsf) {
  const int n = blockIdx.x & 255;
  const int t = threadIdx.x;
  const float* W = (blockIdx.x < 256) ? W2 : W3;
  ushort* dst = (ushort*)(wsf + ((blockIdx.x < 256) ? WS_W2T : WS_W3T));
  dst[n*256 + t] = f2bf(W[t*256 + n]);
}

// h1 = relu(d1 + x @ A1), bf16, swizzled into LDS [64][256].
__device__ __forceinline__ void compute_h1(
    const float (*xs)[4], ushort* h1s, int t,
    const float a1c[4][2], const float d1c[2]) {
  const int c0 = (t & 127) * 2;
  const int r0 = (t >> 7) * 32;
  #pragma unroll 4
  for (int rr = 0; rr < 32; ++rr) {
    const int r = r0 + rr;
    const float x0 = xs[r][0], x1 = xs[r][1], x2 = xs[r][2], x3 = xs[r][3];
    float v0 = d1c[0], v1 = d1c[1];
    v0 = fmaf(x0, a1c[0][0], v0); v1 = fmaf(x0, a1c[0][1], v1);
    v0 = fmaf(x1, a1c[1][0], v0); v1 = fmaf(x1, a1c[1][1], v1);
    v0 = fmaf(x2, a1c[2][0], v0); v1 = fmaf(x2, a1c[2][1], v1);
    v0 = fmaf(x3, a1c[3][0], v0); v1 = fmaf(x3, a1c[3][1], v1);
    v0 = fmaxf(v0, 0.f); v1 = fmaxf(v1, 0.f);
    unsigned int pk = (unsigned int)f2bf(v0) | ((unsigned int)f2bf(v1) << 16);
    unsigned int byte = (unsigned int)r*512u + (unsigned int)c0*2u;
    byte ^= (unsigned int)(r & 7) << 4;
    *(unsigned int*)((char*)h1s + byte) = pk;
  }
}

// Load A fragments (4 rf) for one ks step from swizzled h1s.
__device__ __forceinline__ void load_aF(const ushort* h1s, int lane, int ks,
                                        int kb, short8 aF[4]) {
  #pragma unroll
  for (int rf = 0; rf < 4; ++rf) {
    const int row = rf*16 + (lane & 15);
    unsigned int byte = (unsigned int)row*512u + (unsigned int)((ks*32 + kb)*2);
    byte ^= (unsigned int)(row & 7) << 4;
    aF[rf] = *(const short8*)((const char*)h1s + byte);
  }
}

// GEMM with B streamed from global (L2), depth-2 register prefetch.
__device__ __forceinline__ void gemm_l2(const ushort* h1s,
    const ushort* __restrict__ Wt, int lane, int wave, f32x4 acc[4][4]) {
  const int kb = (lane >> 4) * 8;
  const ushort* wp = Wt + (size_t)(wave*64 + (lane & 15))*256 + kb;
  short8 bbuf[3][4];
  #pragma unroll
  for (int cf = 0; cf < 4; ++cf) {
    bbuf[0][cf] = *(const short8*)(wp + cf*4096);
    bbuf[1][cf] = *(const short8*)(wp + cf*4096 + 32);
  }
  #pragma unroll
  for (int ks = 0; ks < 8; ++ks) {
    if (ks < 6) {
      #pragma unroll
      for (int cf = 0; cf < 4; ++cf)
        bbuf[(ks+2)%3][cf] = *(const short8*)(wp + cf*4096 + (ks+2)*32);
    }
    short8 aF[4];
    load_aF(h1s, lane, ks, kb, aF);
    #pragma unroll
    for (int cf = 0; cf < 4; ++cf)
      #pragma unroll
      for (int rf = 0; rf < 4; ++rf)
        acc[rf][cf] = __builtin_amdgcn_mfma_f32_16x16x32_bf16(
            aF[rf], bbuf[ks%3][cf], acc[rf][cf], 0, 0, 0);
  }
}

// GEMM with B resident in registers.
__device__ __forceinline__ void gemm_reg(const ushort* h1s,
    const short8 B2r[4][8], int lane, f32x4 acc[4][4]) {
  const int kb = (lane >> 4) * 8;
  #pragma unroll
  for (int ks = 0; ks < 8; ++ks) {
    short8 aF[4];
    load_aF(h1s, lane, ks, kb, aF);
    #pragma unroll
    for (int cf = 0; cf < 4; ++cf)
      #pragma unroll
      for (int rf = 0; rf < 4; ++rf)
        acc[rf][cf] = __builtin_amdgcn_mfma_f32_16x16x32_bf16(
            aF[rf], B2r[cf][ks], acc[rf][cf], 0, 0, 0);
  }
}

// Pass A: recompute h1, GEMM2 (B2 in registers), masked sum/sumsq partials.
__global__ __launch_bounds__(256, 2) void stats2_mfma(
    const float* __restrict__ bbox, const void* __restrict__ maskp,
    const int* __restrict__ flagp, const float* wsf,
    const float* __restrict__ b2, float* __restrict__ part2) {
  __shared__ float xs[64][4];
  __shared__ float ms[64];
  __shared__ ushort h1s[64*256];
  const int t = threadIdx.x, lane = t & 63, wave = t >> 6;
  const int fmt = *flagp;
  float a1c[4][2], d1c[2];
  {
    const int c0 = (t & 127) * 2;
    #pragma unroll
    for (int j = 0; j < 4; ++j) {
      a1c[j][0] = wsf[WS_A1 + j*256 + c0];
      a1c[j][1] = wsf[WS_A1 + j*256 + c0 + 1];
    }
    d1c[0] = wsf[WS_D1 + c0]; d1c[1] = wsf[WS_D1 + c0 + 1];
  }
  // Preload all B2 fragments into registers (tile-invariant).
  short8 B2r[4][8];
  {
    const int kb = (lane >> 4) * 8;
    const ushort* wp = (const ushort*)(wsf + WS_W2T) +
                       (size_t)(wave*64 + (lane & 15))*256 + kb;
    #pragma unroll
    for (int cf = 0; cf < 4; ++cf)
      #pragma unroll
      for (int ks = 0; ks < 8; ++ks)
        B2r[cf][ks] = *(const short8*)(wp + cf*4096 + ks*32);
  }
  float b2v[4];
  #pragma unroll
  for (int cf = 0; cf < 4; ++cf) b2v[cf] = b2[wave*64 + cf*16 + (lane & 15)];
  float pS[4] = {0,0,0,0}, pQ[4] = {0,0,0,0};

  for (int tile = blockIdx.x; tile < NTILES; tile += GRID_STATS) {
    const int row0 = tile << 6;
    __syncthreads();
    if (t < 64) {
      float4 x4 = *(const float4*)(bbox + (size_t)(row0 + t) * 16);
      xs[t][0] = x4.x; xs[t][1] = x4.y; xs[t][2] = x4.z; xs[t][3] = x4.w;
      ms[t] = load_mask(maskp, fmt, row0 + t);
    }
    __syncthreads();
    compute_h1(xs, h1s, t, a1c, d1c);
    __syncthreads();
    f32x4 acc[4][4];
    #pragma unroll
    for (int rf = 0; rf < 4; ++rf)
      #pragma unroll
      for (int cf = 0; cf < 4; ++cf)
        acc[rf][cf] = (f32x4){b2v[cf], b2v[cf], b2v[cf], b2v[cf]};
    gemm_reg(h1s, B2r, lane, acc);
    float mr[4][4];
    #pragma unroll
    for (int rf = 0; rf < 4; ++rf)
      #pragma unroll
      for (int r = 0; r < 4; ++r)
        mr[rf][r] = ms[rf*16 + ((lane >> 4) * 4) + r];
    #pragma unroll
    for (int cf = 0; cf < 4; ++cf)
      #pragma unroll
      for (int rf = 0; rf < 4; ++rf)
        #pragma unroll
        for (int r = 0; r < 4; ++r) {
          const float m = mr[rf][r];
          const float v = acc[rf][cf][r];
          pS[cf] = fmaf(m, v, pS[cf]);
          pQ[cf] = fmaf(m*v, v, pQ[cf]);
        }
  }
  #pragma unroll
  for (int cf = 0; cf < 4; ++cf) {
    pS[cf] += __shfl_xor(pS[cf], 16); pS[cf] += __shfl_xor(pS[cf], 32);
    pQ[cf] += __shfl_xor(pQ[cf], 16); pQ[cf] += __shfl_xor(pQ[cf], 32);
  }
  if (lane < 16) {
    #pragma unroll
    for (int cf = 0; cf < 4; ++cf) {
      const int col = wave*64 + cf*16 + lane;
      part2[(size_t)blockIdx.x*512 + col] = pS[cf];
      part2[(size_t)blockIdx.x*512 + 256 + col] = pQ[cf];
    }
  }
}

// Reduce layer-2 BN partials (one block per feature), write a2/c2.
__global__ __launch_bounds__(256) void finalize2_kernel(
    float* __restrict__ wsf, const float* __restrict__ g2,
    const float* __restrict__ be2) {
  const int f = blockIdx.x, t = threadIdx.x;
  const float* part2 = wsf + WS_P2;
  float s1 = 0.f, s2 = 0.f;
  for (int b = t; b < GRID_STATS; b += 256) {
    s1 += part2[(size_t)b*512 + f];
    s2 += part2[(size_t)b*512 + 256 + f];
  }
  __shared__ float r1[256], r2[256];
  r1[t] = s1; r2[t] = s2;
  __syncthreads();
  for (int off = 128; off > 0; off >>= 1) {
    if (t < off) { r1[t] += r1[t+off]; r2[t] += r2[t+off]; }
    __syncthreads();
  }
  if (t == 0) {
    const float cnt = wsf[WS_CNT];
    const float mu  = r1[0]/cnt;
    const float var = fmaxf(r2[0]/cnt - mu*mu, 0.f);
    const float a2  = g2[f] * rsqrtf(var + BN_EPS_F);
    wsf[WS_A2 + f] = a2;
    wsf[WS_C2 + f] = be2[f] - mu*a2;
  }
}

// Pass B: h1 -> GEMM2 -> BN2+ReLU -> GEMM3 -> mask -> NT-store out.
__global__ __launch_bounds__(256, 2) void mlp3_mfma(
    const float* __restrict__ bbox, const void* __restrict__ maskp,
    const int* __restrict__ flagp, const float* wsf,
    const float* __restrict__ b2, const float* __restrict__ b3,
    float* __restrict__ out) {
  __shared__ float xs[64][4];
  __shared__ float ms[64];
  __shared__ ushort h1s[64*256];   // also reused as 16KB fp32 C-staging
  const int t = threadIdx.x, lane = t & 63, wave = t >> 6;
  const int fmt = *flagp;
  float a1c[4][2], d1c[2];
  {
    const int c0 = (t & 127) * 2;
    #pragma unroll
    for (int j = 0; j < 4; ++j) {
      a1c[j][0] = wsf[WS_A1 + j*256 + c0];
      a1c[j][1] = wsf[WS_A1 + j*256 + c0 + 1];
    }
    d1c[0] = wsf[WS_D1 + c0]; d1c[1] = wsf[WS_D1 + c0 + 1];
  }
  const ushort* W2T = (const ushort*)(wsf + WS_W2T);
  const ushort* W3T = (const ushort*)(wsf + WS_W3T);
  float b2v[4], b3v[4], a2v[4], c2v[4];
  #pragma unroll
  for (int cf = 0; cf < 4; ++cf) {
    const int col = wave*64 + cf*16 + (lane & 15);
    b2v[cf] = b2[col]; b3v[cf] = b3[col];
    a2v[cf] = wsf[WS_A2 + col]; c2v[cf] = wsf[WS_C2 + col];
  }
  float* cst = (float*)h1s;

  for (int tile = blockIdx.x; tile < NTILES; tile += GRID_MLP) {
    const int row0 = tile << 6;
    __syncthreads();
    if (t < 64) {
      float4 x4 = *(const float4*)(bbox + (size_t)(row0 + t) * 16);
      xs[t][0] = x4.x; xs[t][1] = x4.y; xs[t][2] = x4.z; xs[t][3] = x4.w;
      ms[t] = load_mask(maskp, fmt, row0 + t);
    }
    __syncthreads();
    compute_h1(xs, h1s, t, a1c, d1c);
    __syncthreads();
    f32x4 acc[4][4];
    #pragma unroll
    for (int rf = 0; rf < 4; ++rf)
      #pragma unroll
      for (int cf = 0; cf < 4; ++cf)
        acc[rf][cf] = (f32x4){b2v[cf], b2v[cf], b2v[cf], b2v[cf]};
    gemm_l2(h1s, W2T, lane, wave, acc);
    // BN2 + ReLU -> h2 (bf16) overwrites h1s
    __syncthreads();
    #pragma unroll
    for (int rf = 0; rf < 4; ++rf)
      #pragma unroll
      for (int cf = 0; cf < 4; ++cf) {
        const int col = wave*64 + cf*16 + (lane & 15);
        #pragma unroll
        for (int r = 0; r < 4; ++r) {
          const float v = fmaxf(fmaf(acc[rf][cf][r], a2v[cf], c2v[cf]), 0.f);
          const int row = rf*16 + ((lane >> 4) * 4) + r;
          unsigned int byte = (unsigned int)row*512u + (unsigned int)col*2u;
          byte ^= (unsigned int)(row & 7) << 4;
          *(ushort*)((char*)h1s + byte) = f2bf(v);
        }
      }
    __syncthreads();
    #pragma unroll
    for (int rf = 0; rf < 4; ++rf)
      #pragma unroll
      for (int cf = 0; cf < 4; ++cf)
        acc[rf][cf] = (f32x4){b3v[cf], b3v[cf], b3v[cf], b3v[cf]};
    gemm_l2(h1s, W3T, lane, wave, acc);
    // C-write: per rf, transpose acc through swizzled LDS, NT full-line store.
    #pragma unroll
    for (int rf = 0; rf < 4; ++rf) {
      __syncthreads();
      #pragma unroll
      for (int cf = 0; cf < 4; ++cf) {
        const int col = wave*64 + cf*16 + (lane & 15);
        #pragma unroll
        for (int r = 0; r < 4; ++r) {
          const int row = ((lane >> 4) << 2) + r;   // 0..15 within rf slab
          *(float*)((char*)cst + cswz((unsigned)row*1024u + (unsigned)col*4u)) =
              acc[rf][cf][r];
        }
      }
      __syncthreads();
      const int row = t >> 4, cg = t & 15;
      const float m = ms[rf*16 + row];
      float* orow = out + (size_t)(row0 + rf*16 + row)*256;
      #pragma unroll
      for (int j = 0; j < 4; ++j) {
        f32x4 v = *(f32x4*)((char*)cst + cswz((unsigned)row*1024u +
                                              (unsigned)cg*16u + (unsigned)j*256u));
        v *= m;
        __builtin_nontemporal_store(v, (f32x4*)(orow + cg*4 + j*64));
      }
    }
  }
}

extern "C" void kernel_launch(void* const* d_in, const int* in_sizes, int n_in,
                              void* d_out, int out_size, void* d_ws, size_t ws_size,
                              hipStream_t stream) {
  (void)in_sizes; (void)n_in; (void)out_size; (void)ws_size;
  const float* bbox = (const float*)d_in[0];
  const void*  maskp= d_in[1];
  const float* W1 = (const float*)d_in[2];
  const float* b1 = (const float*)d_in[3];
  const float* g1 = (const float*)d_in[4];
  const float* be1= (const float*)d_in[5];
  const float* W2 = (const float*)d_in[6];
  const float* b2 = (const float*)d_in[7];
  const float* g2 = (const float*)d_in[8];
  const float* be2= (const float*)d_in[9];
  const float* W3 = (const float*)d_in[10];
  const float* b3 = (const float*)d_in[11];
  float* out = (float*)d_out;
  float* wsf = (float*)d_ws;
  int*   flag= (int*)d_ws;

  hipLaunchKernelGGL(detect_mask_kernel, dim3(1), dim3(256), 0, stream,
                     (const unsigned char*)maskp, flag);
  hipLaunchKernelGGL(stats1_kernel, dim3(256), dim3(256), 0, stream,
                     bbox, maskp, flag, wsf + WS_P1);
  hipLaunchKernelGGL(finalize1_kernel, dim3(1), dim3(256), 0, stream,
                     wsf + WS_P1, W1, b1, g1, be1, wsf);
  hipLaunchKernelGGL(prep_weights, dim3(512), dim3(256), 0, stream,
                     W2, W3, wsf);
  hipLaunchKernelGGL(stats2_mfma, dim3(GRID_STATS), dim3(256), 0, stream,
                     bbox, maskp, flag, wsf, b2, wsf + WS_P2);
  hipLaunchKernelGGL(finalize2_kernel, dim3(256), dim3(256), 0, stream,
                     wsf, g2, be2);
  hipLaunchKernelGGL(mlp3_mfma, dim3(GRID_MLP), dim3(256), 0, stream,
                     bbox, maskp, flag, wsf, b2, b3, out);
}

// Round 5
// 217.140 us; speedup vs baseline: 4.5009x; 2.1625x over previous
//
#include <hip/hip_runtime.h>

typedef __attribute__((ext_vector_type(8))) short short8;
typedef __attribute__((ext_vector_type(4))) float f32x4;

#define M_ROWS (512*512)
#define NTILES (M_ROWS/64)
#define GRID_STATS 512
#define GRID_MLP 256
#define TILES_PER_BLK (NTILES/GRID_MLP)   // 16
#define BN_EPS_F 1e-5f

// ws layout in float units
#define WS_FLAG 0
#define WS_P1   64        // 256 blocks * 24 floats (stats1 partials)
#define WS_CNT  8192
#define WS_A1   8256      // 4*256 folded W1*a1
#define WS_D1   9280      // 256 folded bias
#define WS_A2   9536      // 256
#define WS_C2   9792      // 256
#define WS_W2T  10240     // ushort[65536] = 32768 floats (W2^T bf16 [n][k])
#define WS_W3T  43008     // ushort[65536]
#define WS_P2   76800     // 512 blocks * 512 floats (layer2 BN partials)

__device__ __forceinline__ float load_mask(const void* mp, int fmt, int row) {
  return fmt ? (((const unsigned char*)mp)[row] ? 1.f : 0.f)
             : (((const int*)mp)[row] ? 1.f : 0.f);
}

__device__ __forceinline__ ushort f2bf(float f) {
  unsigned int u = __float_as_uint(f);
  u += 0x7FFFu + ((u >> 16) & 1u);   // RNE
  return (ushort)(u >> 16);
}

// LDS-only barrier: does NOT drain vmcnt, so global stores stay in flight.
__device__ __forceinline__ void barrier_lds() {
  __builtin_amdgcn_sched_barrier(0);
  asm volatile("s_waitcnt lgkmcnt(0)");
  __builtin_amdgcn_sched_barrier(0);
  __builtin_amdgcn_s_barrier();
  __builtin_amdgcn_sched_barrier(0);
}

// Detect whether mask buffer is int32 (flag=0) or packed uint8 (flag=1).
__global__ void detect_mask_kernel(const unsigned char* __restrict__ mb,
                                   int* __restrict__ flag) {
  __shared__ int any;
  if (threadIdx.x == 0) any = 0;
  __syncthreads();
  int c = 0;
  for (int i = threadIdx.x; i < 4096; i += blockDim.x)
    if ((i & 3) && mb[i]) c = 1;
  if (c) atomicOr(&any, 1);
  __syncthreads();
  if (threadIdx.x == 0) *flag = any;
}

// Masked sufficient statistics of x: cnt, sum(x), sum(x x^T)
__global__ __launch_bounds__(256) void stats1_kernel(
    const float* __restrict__ bbox, const void* __restrict__ maskp,
    const int* __restrict__ flagp, float* __restrict__ part) {
  const int t = threadIdx.x;
  const int fmt = *flagp;
  float cnt = 0.f, sx[4] = {0.f,0.f,0.f,0.f}, sxx[16];
  #pragma unroll
  for (int i = 0; i < 16; ++i) sxx[i] = 0.f;
  for (int row = blockIdx.x * 256 + t; row < M_ROWS; row += gridDim.x * 256) {
    float m = load_mask(maskp, fmt, row);
    if (m != 0.f) {
      float4 x = *(const float4*)(bbox + (size_t)row * 16);
      float xv[4] = {x.x, x.y, x.z, x.w};
      cnt += 1.f;
      #pragma unroll
      for (int i = 0; i < 4; ++i) {
        sx[i] += xv[i];
        #pragma unroll
        for (int j = 0; j < 4; ++j) sxx[i*4+j] = fmaf(xv[i], xv[j], sxx[i*4+j]);
      }
    }
  }
  __shared__ float rb[256][22];
  rb[t][0] = cnt;
  #pragma unroll
  for (int i = 0; i < 4; ++i) rb[t][1+i] = sx[i];
  #pragma unroll
  for (int i = 0; i < 16; ++i) rb[t][5+i] = sxx[i];
  __syncthreads();
  for (int off = 128; off > 0; off >>= 1) {
    if (t < off) {
      #pragma unroll
      for (int s = 0; s < 21; ++s) rb[t][s] += rb[t+off][s];
    }
    __syncthreads();
  }
  if (t < 21) part[blockIdx.x * 24 + t] = rb[0][t];
}

// Reduce stats1 partials; compute folded layer-1 weights A1 = W1*a1, d1.
__global__ __launch_bounds__(256) void finalize1_kernel(
    const float* __restrict__ part, const float* __restrict__ W1,
    const float* __restrict__ b1, const float* __restrict__ g1,
    const float* __restrict__ be1, float* __restrict__ wsf) {
  const int t = threadIdx.x;
  __shared__ float s[21];
  if (t < 21) {
    float a = 0.f;
    for (int b = 0; b < 256; ++b) a += part[b*24 + t];
    s[t] = a;
  }
  __syncthreads();
  const float cnt = fmaxf(s[0], 1.f);
  float w[4] = {W1[t], W1[256+t], W1[512+t], W1[768+t]};
  const float b1f = b1[t];
  float sw = 0.f;
  #pragma unroll
  for (int k = 0; k < 4; ++k) sw = fmaf(s[1+k], w[k], sw);
  float qf = 0.f;
  #pragma unroll
  for (int i = 0; i < 4; ++i)
    #pragma unroll
    for (int j = 0; j < 4; ++j) qf = fmaf(s[5+i*4+j]*w[i], w[j], qf);
  const float mu  = sw/cnt + b1f;
  const float eh2 = (qf + 2.f*b1f*sw)/cnt + b1f*b1f;
  const float var = fmaxf(eh2 - mu*mu, 0.f);
  const float a1  = g1[t] * rsqrtf(var + BN_EPS_F);
  const float c1  = be1[t] - mu*a1;
  #pragma unroll
  for (int k = 0; k < 4; ++k) wsf[WS_A1 + k*256 + t] = w[k]*a1;
  wsf[WS_D1 + t] = fmaf(b1f, a1, c1);
  if (t == 0) wsf[WS_CNT] = cnt;
}

// Convert W2, W3 (fp32 [k][n]) to bf16 transposed [n][k] in ws.
__global__ __launch_bounds__(256) void prep_weights(
    const float* __restrict__ W2, const float* __restrict__ W3,
    float* __restrict__ wsf) {
  const int n = blockIdx.x & 255;
  const int t = threadIdx.x;
  const float* W = (blockIdx.x < 256) ? W2 : W3;
  ushort* dst = (ushort*)(wsf + ((blockIdx.x < 256) ? WS_W2T : WS_W3T));
  dst[n*256 + t] = f2bf(W[t*256 + n]);
}

// h1 = relu(d1 + x @ A1), bf16, swizzled into LDS [64][256].
__device__ __forceinline__ void compute_h1(
    const float (*xs)[4], ushort* h1s, int t,
    const float a1c[4][2], const float d1c[2]) {
  const int c0 = (t & 127) * 2;
  const int r0 = (t >> 7) * 32;
  #pragma unroll 4
  for (int rr = 0; rr < 32; ++rr) {
    const int r = r0 + rr;
    const f32x4 xv = *(const f32x4*)&xs[r][0];
    float v0 = d1c[0], v1 = d1c[1];
    v0 = fmaf(xv.x, a1c[0][0], v0); v1 = fmaf(xv.x, a1c[0][1], v1);
    v0 = fmaf(xv.y, a1c[1][0], v0); v1 = fmaf(xv.y, a1c[1][1], v1);
    v0 = fmaf(xv.z, a1c[2][0], v0); v1 = fmaf(xv.z, a1c[2][1], v1);
    v0 = fmaf(xv.w, a1c[3][0], v0); v1 = fmaf(xv.w, a1c[3][1], v1);
    v0 = fmaxf(v0, 0.f); v1 = fmaxf(v1, 0.f);
    unsigned int pk = (unsigned int)f2bf(v0) | ((unsigned int)f2bf(v1) << 16);
    unsigned int byte = (unsigned int)r*512u + (unsigned int)c0*2u;
    byte ^= (unsigned int)(r & 7) << 4;
    *(unsigned int*)((char*)h1s + byte) = pk;
  }
}

// Load A fragments (4 rf) for one ks step from swizzled h1s.
__device__ __forceinline__ void load_aF(const ushort* h1s, int lane, int ks,
                                        int kb, short8 aF[4]) {
  #pragma unroll
  for (int rf = 0; rf < 4; ++rf) {
    const int row = rf*16 + (lane & 15);
    unsigned int byte = (unsigned int)row*512u + (unsigned int)((ks*32 + kb)*2);
    byte ^= (unsigned int)(row & 7) << 4;
    aF[rf] = *(const short8*)((const char*)h1s + byte);
  }
}

// GEMM with B resident in registers.
__device__ __forceinline__ void gemm_reg(const ushort* h1s,
    const short8 Br[4][8], int lane, f32x4 acc[4][4]) {
  const int kb = (lane >> 4) * 8;
  #pragma unroll
  for (int ks = 0; ks < 8; ++ks) {
    short8 aF[4];
    load_aF(h1s, lane, ks, kb, aF);
    #pragma unroll
    for (int cf = 0; cf < 4; ++cf)
      #pragma unroll
      for (int rf = 0; rf < 4; ++rf)
        acc[rf][cf] = __builtin_amdgcn_mfma_f32_16x16x32_bf16(
            aF[rf], Br[cf][ks], acc[rf][cf], 0, 0, 0);
  }
}

// Load all B fragments of one weight matrix into registers.
__device__ __forceinline__ void load_B(const ushort* __restrict__ Wt,
                                       int lane, int wave, short8 Br[4][8]) {
  const int kb = (lane >> 4) * 8;
  const ushort* wp = Wt + (size_t)(wave*64 + (lane & 15))*256 + kb;
  #pragma unroll
  for (int cf = 0; cf < 4; ++cf)
    #pragma unroll
    for (int ks = 0; ks < 8; ++ks)
      Br[cf][ks] = *(const short8*)(wp + cf*4096 + ks*32);
}

// Pass A: recompute h1, GEMM2 (B2 in registers), masked sum/sumsq partials.
__global__ __launch_bounds__(256, 2) void stats2_mfma(
    const float* __restrict__ bbox, const void* __restrict__ maskp,
    const int* __restrict__ flagp, const float* wsf,
    const float* __restrict__ b2, float* __restrict__ part2) {
  __shared__ float xs[64][4];
  __shared__ float ms[64];
  __shared__ ushort h1s[64*256];
  const int t = threadIdx.x, lane = t & 63, wave = t >> 6;
  const int fmt = *flagp;
  float a1c[4][2], d1c[2];
  {
    const int c0 = (t & 127) * 2;
    #pragma unroll
    for (int j = 0; j < 4; ++j) {
      a1c[j][0] = wsf[WS_A1 + j*256 + c0];
      a1c[j][1] = wsf[WS_A1 + j*256 + c0 + 1];
    }
    d1c[0] = wsf[WS_D1 + c0]; d1c[1] = wsf[WS_D1 + c0 + 1];
  }
  short8 B2r[4][8];
  load_B((const ushort*)(wsf + WS_W2T), lane, wave, B2r);
  float b2v[4];
  #pragma unroll
  for (int cf = 0; cf < 4; ++cf) b2v[cf] = b2[wave*64 + cf*16 + (lane & 15)];
  float pS[4] = {0,0,0,0}, pQ[4] = {0,0,0,0};

  for (int tile = blockIdx.x; tile < NTILES; tile += GRID_STATS) {
    const int row0 = tile << 6;
    __syncthreads();
    if (t < 64) {
      float4 x4 = *(const float4*)(bbox + (size_t)(row0 + t) * 16);
      xs[t][0] = x4.x; xs[t][1] = x4.y; xs[t][2] = x4.z; xs[t][3] = x4.w;
      ms[t] = load_mask(maskp, fmt, row0 + t);
    }
    __syncthreads();
    compute_h1(xs, h1s, t, a1c, d1c);
    __syncthreads();
    f32x4 acc[4][4];
    #pragma unroll
    for (int rf = 0; rf < 4; ++rf)
      #pragma unroll
      for (int cf = 0; cf < 4; ++cf)
        acc[rf][cf] = (f32x4){b2v[cf], b2v[cf], b2v[cf], b2v[cf]};
    gemm_reg(h1s, B2r, lane, acc);
    float mr[4][4];
    #pragma unroll
    for (int rf = 0; rf < 4; ++rf)
      #pragma unroll
      for (int r = 0; r < 4; ++r)
        mr[rf][r] = ms[rf*16 + ((lane >> 4) * 4) + r];
    #pragma unroll
    for (int cf = 0; cf < 4; ++cf)
      #pragma unroll
      for (int rf = 0; rf < 4; ++rf)
        #pragma unroll
        for (int r = 0; r < 4; ++r) {
          const float m = mr[rf][r];
          const float v = acc[rf][cf][r];
          pS[cf] = fmaf(m, v, pS[cf]);
          pQ[cf] = fmaf(m*v, v, pQ[cf]);
        }
  }
  #pragma unroll
  for (int cf = 0; cf < 4; ++cf) {
    pS[cf] += __shfl_xor(pS[cf], 16); pS[cf] += __shfl_xor(pS[cf], 32);
    pQ[cf] += __shfl_xor(pQ[cf], 16); pQ[cf] += __shfl_xor(pQ[cf], 32);
  }
  if (lane < 16) {
    #pragma unroll
    for (int cf = 0; cf < 4; ++cf) {
      const int col = wave*64 + cf*16 + lane;
      part2[(size_t)blockIdx.x*512 + col] = pS[cf];
      part2[(size_t)blockIdx.x*512 + 256 + col] = pQ[cf];
    }
  }
}

// Reduce layer-2 BN partials (one block per feature), write a2/c2.
__global__ __launch_bounds__(256) void finalize2_kernel(
    float* __restrict__ wsf, const float* __restrict__ g2,
    const float* __restrict__ be2) {
  const int f = blockIdx.x, t = threadIdx.x;
  const float* part2 = wsf + WS_P2;
  float s1 = 0.f, s2 = 0.f;
  for (int b = t; b < GRID_STATS; b += 256) {
    s1 += part2[(size_t)b*512 + f];
    s2 += part2[(size_t)b*512 + 256 + f];
  }
  __shared__ float r1[256], r2[256];
  r1[t] = s1; r2[t] = s2;
  __syncthreads();
  for (int off = 128; off > 0; off >>= 1) {
    if (t < off) { r1[t] += r1[t+off]; r2[t] += r2[t+off]; }
    __syncthreads();
  }
  if (t == 0) {
    const float cnt = wsf[WS_CNT];
    const float mu  = r1[0]/cnt;
    const float var = fmaxf(r2[0]/cnt - mu*mu, 0.f);
    const float a2  = g2[f] * rsqrtf(var + BN_EPS_F);
    wsf[WS_A2 + f] = a2;
    wsf[WS_C2 + f] = be2[f] - mu*a2;
  }
}

// Pass B: h1 -> GEMM2 -> BN2+ReLU -> GEMM3 -> mask -> store.
// B2 AND B3 live in registers for the whole kernel; x/mask preloaded to LDS;
// the ONLY global traffic in the main loop is the C-store stream, which is
// never vmcnt-drained (raw s_barrier, LDS-only waits).
__global__ __launch_bounds__(256, 1) void mlp3_mfma(
    const float* __restrict__ bbox, const void* __restrict__ maskp,
    const int* __restrict__ flagp, const float* wsf,
    const float* __restrict__ b2, const float* __restrict__ b3,
    float* __restrict__ out) {
  __shared__ ushort h1s[64*256];            // 32KB swizzled bf16 h tile
  __shared__ float xst[TILES_PER_BLK*64][4];// 16KB
  __shared__ float mst[TILES_PER_BLK*64];   // 4KB
  const int t = threadIdx.x, lane = t & 63, wave = t >> 6;
  const int fmt = *flagp;
  const int row_base = blockIdx.x * (TILES_PER_BLK*64);

  // one-time preload: x and mask for all tiles of this block
  #pragma unroll
  for (int i = 0; i < TILES_PER_BLK*64/256; ++i) {
    const int r = i*256 + t;
    float4 x4 = *(const float4*)(bbox + (size_t)(row_base + r) * 16);
    xst[r][0] = x4.x; xst[r][1] = x4.y; xst[r][2] = x4.z; xst[r][3] = x4.w;
    mst[r] = load_mask(maskp, fmt, row_base + r);
  }
  float a1c[4][2], d1c[2];
  {
    const int c0 = (t & 127) * 2;
    #pragma unroll
    for (int j = 0; j < 4; ++j) {
      a1c[j][0] = wsf[WS_A1 + j*256 + c0];
      a1c[j][1] = wsf[WS_A1 + j*256 + c0 + 1];
    }
    d1c[0] = wsf[WS_D1 + c0]; d1c[1] = wsf[WS_D1 + c0 + 1];
  }
  short8 B2r[4][8], B3r[4][8];
  load_B((const ushort*)(wsf + WS_W2T), lane, wave, B2r);
  load_B((const ushort*)(wsf + WS_W3T), lane, wave, B3r);
  float b2v[4], b3v[4], a2v[4], c2v[4];
  #pragma unroll
  for (int cf = 0; cf < 4; ++cf) {
    const int col = wave*64 + cf*16 + (lane & 15);
    b2v[cf] = b2[col]; b3v[cf] = b3[col];
    a2v[cf] = wsf[WS_A2 + col]; c2v[cf] = wsf[WS_C2 + col];
  }
  __syncthreads();   // one-time full barrier (preloads visible)

  for (int tile = 0; tile < TILES_PER_BLK; ++tile) {
    const int r0 = tile * 64;
    // h1 for this tile (xst is read-only; h1s protected by loop-top order:
    // previous tile's gemm3 reads completed before the last barrier_lds)
    compute_h1(&xst[r0], h1s, t, a1c, d1c);
    barrier_lds();
    f32x4 acc[4][4];
    #pragma unroll
    for (int rf = 0; rf < 4; ++rf)
      #pragma unroll
      for (int cf = 0; cf < 4; ++cf)
        acc[rf][cf] = (f32x4){b2v[cf], b2v[cf], b2v[cf], b2v[cf]};
    gemm_reg(h1s, B2r, lane, acc);
    barrier_lds();   // everyone done reading h1s -> safe to overwrite
    // BN2 + ReLU -> h2 (bf16) overwrites h1s
    #pragma unroll
    for (int rf = 0; rf < 4; ++rf)
      #pragma unroll
      for (int cf = 0; cf < 4; ++cf) {
        const int col = wave*64 + cf*16 + (lane & 15);
        #pragma unroll
        for (int r = 0; r < 4; ++r) {
          const float v = fmaxf(fmaf(acc[rf][cf][r], a2v[cf], c2v[cf]), 0.f);
          const int row = rf*16 + ((lane >> 4) * 4) + r;
          unsigned int byte = (unsigned int)row*512u + (unsigned int)col*2u;
          byte ^= (unsigned int)(row & 7) << 4;
          *(ushort*)((char*)h1s + byte) = f2bf(v);
        }
      }
    barrier_lds();
    #pragma unroll
    for (int rf = 0; rf < 4; ++rf)
      #pragma unroll
      for (int cf = 0; cf < 4; ++cf)
        acc[rf][cf] = (f32x4){b3v[cf], b3v[cf], b3v[cf], b3v[cf]};
    gemm_reg(h1s, B3r, lane, acc);
    // masked store straight from acc (no vmcnt wait ever in this loop)
    float mr[4][4];
    #pragma unroll
    for (int rf = 0; rf < 4; ++rf)
      #pragma unroll
      for (int r = 0; r < 4; ++r)
        mr[rf][r] = mst[r0 + rf*16 + ((lane >> 4) * 4) + r];
    #pragma unroll
    for (int rf = 0; rf < 4; ++rf)
      #pragma unroll
      for (int cf = 0; cf < 4; ++cf) {
        const int col = wave*64 + cf*16 + (lane & 15);
        #pragma unroll
        for (int r = 0; r < 4; ++r) {
          const int lrow = rf*16 + ((lane >> 4) * 4) + r;
          out[(size_t)(row_base + r0 + lrow)*256 + col] =
              acc[rf][cf][r] * mr[rf][r];
        }
      }
    barrier_lds();   // gemm3 reads + mst reads done -> next tile may write h1s
  }
}

extern "C" void kernel_launch(void* const* d_in, const int* in_sizes, int n_in,
                              void* d_out, int out_size, void* d_ws, size_t ws_size,
                              hipStream_t stream) {
  (void)in_sizes; (void)n_in; (void)out_size; (void)ws_size;
  const float* bbox = (const float*)d_in[0];
  const void*  maskp= d_in[1];
  const float* W1 = (const float*)d_in[2];
  const float* b1 = (const float*)d_in[3];
  const float* g1 = (const float*)d_in[4];
  const float* be1= (const float*)d_in[5];
  const float* W2 = (const float*)d_in[6];
  const float* b2 = (const float*)d_in[7];
  const float* g2 = (const float*)d_in[8];
  const float* be2= (const float*)d_in[9];
  const float* W3 = (const float*)d_in[10];
  const float* b3 = (const float*)d_in[11];
  float* out = (float*)d_out;
  float* wsf = (float*)d_ws;
  int*   flag= (int*)d_ws;

  hipLaunchKernelGGL(detect_mask_kernel, dim3(1), dim3(256), 0, stream,
                     (const unsigned char*)maskp, flag);
  hipLaunchKernelGGL(stats1_kernel, dim3(256), dim3(256), 0, stream,
                     bbox, maskp, flag, wsf + WS_P1);
  hipLaunchKernelGGL(finalize1_kernel, dim3(1), dim3(256), 0, stream,
                     wsf + WS_P1, W1, b1, g1, be1, wsf);
  hipLaunchKernelGGL(prep_weights, dim3(512), dim3(256), 0, stream,
                     W2, W3, wsf);
  hipLaunchKernelGGL(stats2_mfma, dim3(GRID_STATS), dim3(256), 0, stream,
                     bbox, maskp, flag, wsf, b2, wsf + WS_P2);
  hipLaunchKernelGGL(finalize2_kernel, dim3(256), dim3(256), 0, stream,
                     wsf, g2, be2);
  hipLaunchKernelGGL(mlp3_mfma, dim3(GRID_MLP), dim3(256), 0, stream,
                     bbox, maskp, flag, wsf, b2, b3, out);
}